// Round 9
// baseline (271.500 us; speedup 1.0000x reference)
//
#include <hip/hip_runtime.h>
#include <hip/hip_bf16.h>
#include <cstdint>

#define BB 2
#define SS 4096
#define DD 768
#define HH 12
#define GG 64
#define WW 256

typedef __hip_bfloat16 bf16;
typedef unsigned short u16;
typedef __attribute__((ext_vector_type(8))) short short8v;
typedef __attribute__((ext_vector_type(4))) float floatx4;
typedef __attribute__((ext_vector_type(16))) float floatx16;

// 0.125 * log2(e): softmax computed with exp2 (v_exp_f32 native)
#define QSCALE 0.18033688011112042f

__device__ __forceinline__ float b2f(u16 u) {
  return __uint_as_float(((unsigned int)u) << 16);
}
__device__ __forceinline__ u16 f2bu(float f) {
  bf16 h = __float2bfloat16(f);
  return *reinterpret_cast<u16*>(&h);
}
__device__ __forceinline__ void async_copy16(const u16* g, u16* l) {
  __builtin_amdgcn_global_load_lds(
      (const __attribute__((address_space(1))) void*)g,
      (__attribute__((address_space(3))) void*)l, 16, 0, 0);
}

struct P7 { const void* p[7]; };

// ---- dtype detect (inputs may be fp32 or bf16) ----
__global__ __launch_bounds__(256) void detect_dtype(const u16* __restrict__ q,
                                                    int* __restrict__ flag) {
  __shared__ int cnt;
  int tid = threadIdx.x;
  if (tid == 0) cnt = 0;
  __syncthreads();
  int bad = 0;
#pragma unroll
  for (int i = 0; i < 16; ++i) {
    float f = b2f(q[tid * 16 + i]);
    if (!isfinite(f) || fabsf(f) > 100.f) bad++;
  }
  atomicAdd(&cnt, bad);
  __syncthreads();
  if (tid == 0) *flag = (cnt > 256) ? 1 : 0;
}

// ---- fused prep: z<7 -> transpose W_z (32x32 tiles); z==7 -> canon query
// (vectorized x8); z==8 -> canon 7 biases. (round-6 verified)
__global__ __launch_bounds__(256) void prep(P7 wsrc, P7 bsrc,
                                            const void* __restrict__ qsrc,
                                            bf16* __restrict__ cWt,
                                            bf16* __restrict__ cB,
                                            bf16* __restrict__ cQ,
                                            const int* __restrict__ flag) {
  bool f32 = (*flag != 0);
  int z = blockIdx.z;
  if (z < 7) {
    __shared__ float tile[32][33];
    const void* src = wsrc.p[z];
    bf16* d = cWt + (size_t)z * DD * DD;
    int tx = threadIdx.x & 31, ty = threadIdx.x >> 5;
    int k0 = blockIdx.x * 32, n0 = blockIdx.y * 32;
#pragma unroll
    for (int i = 0; i < 32; i += 8) {
      int k = k0 + ty + i, n = n0 + tx;
      float v = f32 ? ((const float*)src)[(size_t)k * DD + n]
                    : b2f(((const u16*)src)[(size_t)k * DD + n]);
      tile[ty + i][tx] = v;
    }
    __syncthreads();
#pragma unroll
    for (int i = 0; i < 32; i += 8) {
      int n = n0 + ty + i, k = k0 + tx;
      d[(size_t)n * DD + k] = __float2bfloat16(tile[tx][ty + i]);
    }
  } else if (z == 7) {
    int bidx = blockIdx.x + 24 * blockIdx.y;  // 576 blocks
    const int nch = (BB * HH * SS * 64) / 8;  // 8-elem chunks
    u16* cQp = (u16*)cQ;
    for (int c = bidx * 256 + threadIdx.x; c < nch; c += 576 * 256) {
      int i = c * 8;
      if (f32) {
        const float* qs = (const float*)qsrc;
        float4 a = *(const float4*)(qs + i);
        float4 b = *(const float4*)(qs + i + 4);
        ushort4 o1 = make_ushort4(f2bu(a.x), f2bu(a.y), f2bu(a.z), f2bu(a.w));
        ushort4 o2 = make_ushort4(f2bu(b.x), f2bu(b.y), f2bu(b.z), f2bu(b.w));
        *(ushort4*)(cQp + i) = o1;
        *(ushort4*)(cQp + i + 4) = o2;
      } else {
        const u16* qs = (const u16*)qsrc;
        *(ushort4*)(cQp + i) = *(const ushort4*)(qs + i);
        *(ushort4*)(cQp + i + 4) = *(const ushort4*)(qs + i + 4);
      }
    }
  } else {
    int which = blockIdx.x;
    if (which >= 7 || blockIdx.y != 0) return;
    const void* s = bsrc.p[which];
    for (int j = threadIdx.x; j < DD; j += 256)
      cB[which * DD + j] =
          __float2bfloat16(f32 ? ((const float*)s)[j] : b2f(((const u16*)s)[j]));
  }
}

// XOR-swizzled [rows][64] LDS: logical chunk c of row r stored at c ^ (r&7).
// Fragment: rows base+(lane&31), k = kk + (lane>>5)*8 .. +7
__device__ __forceinline__ short8v lda(u16 (*Ls)[64], int base, int lane, int kk) {
  int row = base + (lane & 31);
  int c = (kk >> 3) + (lane >> 5);
  return *(const short8v*)&Ls[row][((c ^ (row & 7)) << 3)];
}

// ---- GEMM core v2 (128x128), single-buffered 2-barrier loop (m97 pattern) ----
__device__ __forceinline__ void gemm_core2(const u16* __restrict__ Xp,
                                           const u16* __restrict__ Wp, int bm,
                                           int bn, int tid, u16 (*As)[64],
                                           u16 (*Bs)[64], floatx16 (&acc)[2][2]) {
  int lane = tid & 63, w = tid >> 6;
  int wm = (w >> 1) * 64, wn = (w & 1) * 64;
  int r8 = lane >> 3;
  int sw = (((lane & 7) ^ (r8 & 7)) << 3);
  for (int k0 = 0; k0 < DD; k0 += 64) {
    __syncthreads();
#pragma unroll
    for (int j = 0; j < 4; ++j) {
      async_copy16(Wp + (size_t)(bn + w * 32 + j * 8 + r8) * DD + k0 + sw,
                   &As[w * 32 + j * 8][0]);
      async_copy16(Xp + (size_t)(bm + w * 32 + j * 8 + r8) * DD + k0 + sw,
                   &Bs[w * 32 + j * 8][0]);
    }
    __syncthreads();
#pragma unroll
    for (int kk = 0; kk < 64; kk += 16) {
      short8v a0 = lda(As, wn, lane, kk);
      short8v a1 = lda(As, wn + 32, lane, kk);
      short8v b0 = lda(Bs, wm, lane, kk);
      short8v b1 = lda(Bs, wm + 32, lane, kk);
      acc[0][0] = __builtin_amdgcn_mfma_f32_32x32x16_bf16(a0, b0, acc[0][0], 0, 0, 0);
      acc[0][1] = __builtin_amdgcn_mfma_f32_32x32x16_bf16(a0, b1, acc[0][1], 0, 0, 0);
      acc[1][0] = __builtin_amdgcn_mfma_f32_32x32x16_bf16(a1, b0, acc[1][0], 0, 0, 0);
      acc[1][1] = __builtin_amdgcn_mfma_f32_32x32x16_bf16(a1, b1, acc[1][1], 0, 0, 0);
    }
  }
}

// ---- Fused 6-projection GEMM, 128x128 tiles, XCD swizzle (round-3 verified).
// which in {2:v, 4:vg} writes TRANSPOSED [bh][d][s] directly (round-8
// verified); tr_vt2 deleted.
__global__ __launch_bounds__(256, 4) void gemm5c(const bf16* __restrict__ Xb,
                                                 const bf16* __restrict__ Wt0,
                                                 const bf16* __restrict__ bset,
                                                 bf16* __restrict__ out0,
                                                 bf16* __restrict__ qgp) {
  __shared__ __align__(16) u16 SH[16384];  // 32 KiB; reused by epilogues
  u16 (*As)[64] = (u16(*)[64])SH;
  u16 (*Bs)[64] = (u16(*)[64])(SH + 8192);
  int tid = threadIdx.x, lane = tid & 63, w = tid >> 6;
  // bijective chunked XCD swizzle over 1926 blocks
  int orig = blockIdx.x;
  const int NWG = 5 * 384 + 6, qq = NWG >> 3, rr = NWG & 7;  // 240, 6
  int xcd = orig & 7, idx = orig >> 3;
  int wg = (xcd < rr ? xcd * (qq + 1) : rr * (qq + 1) + (xcd - rr) * qq) + idx;
  int which, bm, bn;
  if (wg >= 1920) {
    which = 5; bm = 0; bn = (wg - 1920) * 128;
  } else {
    which = wg / 384;
    int rem = wg % 384;
    bm = (rem / 6) * 128;
    bn = (rem % 6) * 128;
  }
  const u16* Wp = (const u16*)Wt0 + (size_t)which * DD * DD;
  const u16* bias = (const u16*)bset + which * DD;
  int Sdim = (which == 5) ? GG : SS;
  u16* outp = (which == 5) ? (u16*)qgp
                           : (u16*)out0 + (size_t)which * BB * HH * SS * 64;
  float scale = (which == 0 || which == 5) ? QSCALE : 1.f;

  floatx16 acc[2][2];
#pragma unroll
  for (int i = 0; i < 2; ++i)
#pragma unroll
    for (int j = 0; j < 2; ++j) acc[i][j] = (floatx16)(0.f);
  gemm_core2((const u16*)Xb, Wp, bm, bn, tid, As, Bs, acc);

  if (which == 2 || which == 4) {
    // ---- transposed epilogue: out[(b*HH+h)*SS*64 + d*SS + s] ----
    const int TST = 132;
    u16* Ct = SH;  // [64][132] = 16896 B
    int h0 = bn >> 6;
    int wm = (w >> 1) * 64;
    int wnl = w & 1;  // ncol half owned by this wave
    int s0 = bm >> 1;
#pragma unroll
    for (int p = 0; p < 2; ++p) {   // head h0+p
      __syncthreads();  // prev-phase LDS reads complete
      if (wnl == p) {
#pragma unroll
        for (int nt = 0; nt < 2; ++nt)
#pragma unroll
          for (int mt = 0; mt < 2; ++mt)
#pragma unroll
            for (int g = 0; g < 4; ++g) {
              int ncl = nt * 32 + g * 8 + ((lane >> 5) << 2);  // d in [0,64)
              ushort4 bi = *(const ushort4*)&bias[bn + p * 64 + ncl];
              int mrow = wm + mt * 32 + (lane & 31);
              Ct[(ncl + 0) * TST + mrow] = f2bu(acc[nt][mt][4 * g + 0] + b2f(bi.x));
              Ct[(ncl + 1) * TST + mrow] = f2bu(acc[nt][mt][4 * g + 1] + b2f(bi.y));
              Ct[(ncl + 2) * TST + mrow] = f2bu(acc[nt][mt][4 * g + 2] + b2f(bi.z));
              Ct[(ncl + 3) * TST + mrow] = f2bu(acc[nt][mt][4 * g + 3] + b2f(bi.w));
            }
      }
      __syncthreads();
      // 2 b x 64 d x 8 chunks(8 s) = 1024 chunks / 256 threads
#pragma unroll
      for (int j = 0; j < 4; ++j) {
        int c = j * 256 + tid;
        int ch = c & 7, rrow = c >> 3;
        int d = rrow >> 1, b = rrow & 1;
        const u16* row = &Ct[d * TST + b];
        ushort4 o1, o2;
        o1.x = row[(ch * 8 + 0) << 1];
        o1.y = row[(ch * 8 + 1) << 1];
        o1.z = row[(ch * 8 + 2) << 1];
        o1.w = row[(ch * 8 + 3) << 1];
        o2.x = row[(ch * 8 + 4) << 1];
        o2.y = row[(ch * 8 + 5) << 1];
        o2.z = row[(ch * 8 + 6) << 1];
        o2.w = row[(ch * 8 + 7) << 1];
        u16* dst = outp + ((size_t)(b * HH + h0 + p)) * (SS * 64) +
                   (size_t)d * SS + s0 + ch * 8;
        *(ushort4*)dst = o1;
        *(ushort4*)(dst + 4) = o2;
      }
    }
    return;
  }

  // ---- heads-layout epilogue (which 0,1,3,5): 2 rounds via LDS ----
  const int CST = 132;  // u16 stride: 264B rows -> 2-way (free) bank pattern
  u16* Cs = SH;         // 64*132 = 8448 u16, fits in SH
  int wn = (w & 1) << 6, wmh = (w >> 1) << 5;
#pragma unroll
  for (int mt = 0; mt < 2; ++mt) {
    __syncthreads();  // prev-phase LDS reads complete
#pragma unroll
    for (int nt = 0; nt < 2; ++nt)
#pragma unroll
      for (int g = 0; g < 4; ++g) {
        int ncol = wn + nt * 32 + g * 8 + ((lane >> 5) << 2);
        ushort4 bi = *(const ushort4*)&bias[bn + ncol];
        int crow = wmh + (lane & 31);
        ushort4 o;
        o.x = f2bu((acc[nt][mt][4 * g + 0] + b2f(bi.x)) * scale);
        o.y = f2bu((acc[nt][mt][4 * g + 1] + b2f(bi.y)) * scale);
        o.z = f2bu((acc[nt][mt][4 * g + 2] + b2f(bi.z)) * scale);
        o.w = f2bu((acc[nt][mt][4 * g + 3] + b2f(bi.w)) * scale);
        *(ushort4*)&Cs[crow * CST + ncol] = o;
      }
    __syncthreads();
    // 64 m-rows x 2 heads x 16 chunks of 8B = 2048 chunks / 256 threads
#pragma unroll
    for (int j = 0; j < 8; ++j) {
      int c = j * 256 + tid;
      int ch = c & 15, mh = c >> 4;
      int mloc = mh >> 1, hloc = mh & 1;
      int m = bm + ((mloc >> 5) << 6) + mt * 32 + (mloc & 31);
      int s = m >> 1, b = m & 1;
      int h = (bn >> 6) + hloc;
      ushort4 vv = *(const ushort4*)&Cs[mloc * CST + hloc * 64 + ch * 4];
      *(ushort4*)(outp + ((size_t)(b * HH + h) * Sdim + s) * 64 + ch * 4) = vv;
    }
  }
}

// Output projection: fp32 flat out[m*768+n], 128x128 tiles.
// R6-verified: coalesced LDS-staged epilogue.
__global__ __launch_bounds__(256, 4) void gemm_out(const bf16* __restrict__ Xb,
                                                   const bf16* __restrict__ Wtb,
                                                   const bf16* __restrict__ biasb,
                                                   float* __restrict__ outv) {
  __shared__ __align__(16) u16 SH[16384];  // As/Bs in K-loop; Cf in epilogue
  u16 (*As)[64] = (u16(*)[64])SH;
  u16 (*Bs)[64] = (u16(*)[64])(SH + 8192);
  float* Cf = (float*)SH;  // [64][128] fp32, chunk-swizzled
  int tid = threadIdx.x, lane = tid & 63, w = tid >> 6;
  int wn = (w & 1) * 64;
  int bm = blockIdx.x * 128, bn = blockIdx.y * 128;
  floatx16 acc[2][2];
#pragma unroll
  for (int i = 0; i < 2; ++i)
#pragma unroll
    for (int j = 0; j < 2; ++j) acc[i][j] = (floatx16)(0.f);
  gemm_core2((const u16*)Xb, (const u16*)Wtb, bm, bn, tid, As, Bs, acc);
  const u16* bias = (const u16*)biasb;
#pragma unroll
  for (int p = 0; p < 2; ++p) {
    __syncthreads();  // prev-phase LDS reads complete
    if ((w >> 1) == p) {
#pragma unroll
      for (int mt = 0; mt < 2; ++mt) {
        int mloc = mt * 32 + (lane & 31);
#pragma unroll
        for (int nt = 0; nt < 2; ++nt)
#pragma unroll
          for (int g = 0; g < 4; ++g) {
            int nl = wn + nt * 32 + g * 8 + ((lane >> 5) << 2);
            ushort4 bi = *(const ushort4*)&bias[bn + nl];
            float4 o;
            o.x = acc[nt][mt][4 * g + 0] + b2f(bi.x);
            o.y = acc[nt][mt][4 * g + 1] + b2f(bi.y);
            o.z = acc[nt][mt][4 * g + 2] + b2f(bi.z);
            o.w = acc[nt][mt][4 * g + 3] + b2f(bi.w);
            int n4 = nl >> 2;
            *(float4*)&Cf[mloc * 128 + ((n4 ^ (mloc & 31)) << 2)] = o;
          }
      }
    }
    __syncthreads();
    // 64 m-rows x 32 chunks of 16B = 2048 chunks / 256 threads
#pragma unroll
    for (int j = 0; j < 8; ++j) {
      int c = j * 256 + tid;
      int mloc = c >> 5, nch = c & 31;
      float4 v = *(const float4*)&Cf[mloc * 128 + ((nch ^ (mloc & 31)) << 2)];
      *(float4*)(outv + (size_t)(bm + p * 64 + mloc) * DD + bn + nch * 4) = v;
    }
  }
}

// ---- MFMA flash attention, 128-row Q tiles, async staging, swapped PV ----
// q pre-scaled by 0.125*log2(e): probabilities via exp2f.
// R9: Ps aliased onto Qs (one PQ[128*72] buffer). Q is staged with the
// identical round-3 pattern (rows of 64 u16, contiguous dest), read into aq
// registers, and is dead before the first Ps write (two __syncthreads later;
// each barrier drains lgkmcnt). LDS 50.7 -> 34.75 KiB => 4 blocks/CU.
__global__ __launch_bounds__(256, 4) void attn_local128(
    const bf16* __restrict__ qb, const bf16* __restrict__ kb,
    const bf16* __restrict__ vtb, const int* __restrict__ kpm,
    bf16* __restrict__ attnout) {
  __shared__ __align__(16) u16 PQ[128 * 72];  // Ps[128][72]; Qs[128][64] alias
  __shared__ __align__(16) u16 Ks[64][64];
  __shared__ __align__(16) u16 Vt[64][64];  // [d][key]
  __shared__ float Ls[128];
  __shared__ int kbadS[64];
  int bid = blockIdx.x;
  int tile = bid & 31, bh = bid >> 5;
  int b = bh / HH, h = bh % HH;
  int tid = threadIdx.x, lane = tid & 63, w = tid >> 6;
  int quad = lane >> 4, t = lane & 15;
  const u16* qp = (const u16*)qb + (size_t)bh * SS * 64;
  const u16* kp = (const u16*)kb + (size_t)bh * SS * 64;
  const u16* vp = (const u16*)vtb + (size_t)bh * SS * 64;  // rows are d
  int sq0 = GG + tile * 128;
#pragma unroll
  for (int j = 0; j < 4; ++j) {
    int qr = sq0 + w * 32 + j * 8 + (lane >> 3);
    int sr = qr < SS ? qr : SS - 1;
    async_copy16(qp + (size_t)sr * 64 + (lane & 7) * 8, &PQ[(w * 32 + j * 8) * 64]);
  }
  __syncthreads();
  short8v aq[2][2];
#pragma unroll
  for (int st = 0; st < 2; ++st)
#pragma unroll
    for (int ks = 0; ks < 2; ++ks)
      aq[st][ks] =
          *(const short8v*)&PQ[(w * 32 + st * 16 + t) * 64 + ks * 32 + quad * 8];
  floatx4 O[2][4];
#pragma unroll
  for (int st = 0; st < 2; ++st)
#pragma unroll
    for (int dt = 0; dt < 4; ++dt) O[st][dt] = (floatx4)(0.f);
  float ps[2][4] = {};
  int win_lo = max(sq0 - WW, GG);
  int win_hi = min(sq0 + 127 + WW, SS - 1);
  int kb_lo = win_lo & ~63;
  int iters = ((win_hi - kb_lo) >> 6) + 2;  // +1: global-keys block
  for (int it = 0; it < iters; ++it) {
    int kbs = (it == 0) ? 0 : kb_lo + ((it - 1) << 6);
    __syncthreads();  // also fences aq ds_reads (lgkm drained at barrier)
#pragma unroll
    for (int j = 0; j < 2; ++j) {
      async_copy16(kp + (size_t)(kbs + w * 16 + j * 8 + (lane >> 3)) * 64 +
                       (lane & 7) * 8,
                   &Ks[w * 16 + j * 8][0]);
      async_copy16(vp + (size_t)(w * 16 + j * 8 + (lane >> 3)) * SS + kbs +
                       (lane & 7) * 8,
                   &Vt[w * 16 + j * 8][0]);
    }
    if (tid < 64) kbadS[tid] = kpm[b * SS + kbs + tid];
    __syncthreads();
#pragma unroll
    for (int st = 0; st < 2; ++st) {
      floatx4 S[4];
#pragma unroll
      for (int nt = 0; nt < 4; ++nt) {
        S[nt] = (floatx4)(0.f);
#pragma unroll
        for (int ks = 0; ks < 2; ++ks) {
          short8v bk = *(const short8v*)&Ks[nt * 16 + t][ks * 32 + quad * 8];
          S[nt] = __builtin_amdgcn_mfma_f32_16x16x32_bf16(aq[st][ks], bk, S[nt],
                                                          0, 0, 0);
        }
      }
      int prow = w * 32 + st * 16 + quad * 4;
      if (it == 0) {
#pragma unroll
        for (int nt = 0; nt < 4; ++nt)
#pragma unroll
          for (int r = 0; r < 4; ++r) {
            float p = exp2f(S[nt][r]);
            ps[st][r] += p;
            PQ[(prow + r) * 72 + (((nt ^ quad) << 4) + t)] = f2bu(p);
          }
      } else {
#pragma unroll
        for (int r = 0; r < 4; ++r) {
          int qr = sq0 + prow + r;
          int off = kbs + t + WW - qr;
#pragma unroll
          for (int nt = 0; nt < 4; ++nt) {
            int bad = kbadS[nt * 16 + t];
            unsigned u = (unsigned)(off + nt * 16);
            float p = exp2f((u <= 2 * WW && bad == 0) ? S[nt][r] : -3.0e38f);
            ps[st][r] += p;
            PQ[(prow + r) * 72 + (((nt ^ quad) << 4) + t)] = f2bu(p);
          }
        }
      }
    }
    short8v ap[2][2];
#pragma unroll
    for (int st = 0; st < 2; ++st)
#pragma unroll
      for (int ks = 0; ks < 2; ++ks) {
        int chunk = (2 * ks + (quad >> 1)) ^ ((t >> 2) & 3);
        ap[st][ks] = *(const short8v*)&PQ[(w * 32 + st * 16 + t) * 72 +
                                          ((chunk << 4) + ((quad & 1) << 3))];
      }
#pragma unroll
    for (int dt = 0; dt < 4; ++dt) {
#pragma unroll
      for (int ks = 0; ks < 2; ++ks) {
        short8v av = *(const short8v*)&Vt[dt * 16 + t][ks * 32 + quad * 8];
#pragma unroll
        for (int st = 0; st < 2; ++st)
          O[st][dt] = __builtin_amdgcn_mfma_f32_16x16x32_bf16(av, ap[st][ks],
                                                              O[st][dt], 0, 0, 0);
      }
    }
  }
#pragma unroll
  for (int st = 0; st < 2; ++st) {
#pragma unroll
    for (int r = 0; r < 4; ++r)
#pragma unroll
      for (int off = 1; off < 16; off <<= 1) ps[st][r] += __shfl_xor(ps[st][r], off);
    if (t == 0)
#pragma unroll
      for (int r = 0; r < 4; ++r) Ls[w * 32 + st * 16 + quad * 4 + r] = ps[st][r];
  }
#pragma unroll
  for (int st = 0; st < 2; ++st) {
    int q = sq0 + w * 32 + st * 16 + t;
    if (q < SS) {
      float linv = 1.0f / Ls[w * 32 + st * 16 + t];
#pragma unroll
      for (int dt = 0; dt < 4; ++dt) {
        ushort4 o;
        o.x = f2bu(O[st][dt][0] * linv);
        o.y = f2bu(O[st][dt][1] * linv);
        o.z = f2bu(O[st][dt][2] * linv);
        o.w = f2bu(O[st][dt][3] * linv);
        *(ushort4*)((u16*)attnout + ((size_t)q * BB + b) * DD + h * 64 +
                    dt * 16 + quad * 4) = o;
      }
    }
  }
}

// Global-row attention (rows < G), 256-key segment per block; fp32 partials.
__global__ __launch_bounds__(256) void attn_glb(
    const bf16* __restrict__ qgb, const bf16* __restrict__ kgb,
    const bf16* __restrict__ vtb, const int* __restrict__ kpm,
    float* __restrict__ part) {
  __shared__ __align__(16) u16 Qs[64][72];
  __shared__ __align__(16) u16 Ks[64][72];
  __shared__ __align__(16) u16 Vt[64][72];
  __shared__ __align__(16) u16 Ps[64][72];
  __shared__ int kbadS[64];
  int bid = blockIdx.x;
  int bh = bid >> 4, seg = bid & 15;
  int b = bh / HH;
  int tid = threadIdx.x, lane = tid & 63, w = tid >> 6;
  int quad = lane >> 4, t = lane & 15;
  const u16* qp = (const u16*)qgb + (size_t)bh * GG * 64;
  const u16* kp = (const u16*)kgb + (size_t)bh * SS * 64;
  const u16* vp = (const u16*)vtb + (size_t)bh * SS * 64;  // rows are d
  int srow = tid >> 2, scol = (tid & 3) * 16;
#pragma unroll
  for (int i = 0; i < 4; ++i)
    *(ushort4*)&Qs[srow][scol + 4 * i] =
        *(const ushort4*)(qp + (size_t)srow * 64 + scol + 4 * i);
  __syncthreads();
  short8v aq[2];
#pragma unroll
  for (int ks = 0; ks < 2; ++ks)
    aq[ks] = *(const short8v*)&Qs[16 * w + t][ks * 32 + quad * 8];
  floatx4 O[4];
#pragma unroll
  for (int i = 0; i < 4; ++i) O[i] = (floatx4)(0.f);
  float ps[4] = {0.f, 0.f, 0.f, 0.f};
  for (int it = 0; it < 4; ++it) {
    int kbs = (seg << 8) + (it << 6);
    ushort4 ku[4], vu[4];
#pragma unroll
    for (int i = 0; i < 4; ++i) {
      ku[i] = *(const ushort4*)(kp + (size_t)(kbs + srow) * 64 + scol + 4 * i);
      vu[i] = *(const ushort4*)(vp + (size_t)srow * SS + kbs + scol + 4 * i);
    }
    int kbval = (tid < 64) ? kpm[b * SS + kbs + tid] : 0;
    __syncthreads();
#pragma unroll
    for (int i = 0; i < 4; ++i) {
      *(ushort4*)&Ks[srow][scol + 4 * i] = ku[i];
      *(ushort4*)&Vt[srow][scol + 4 * i] = vu[i];
    }
    if (tid < 64) kbadS[tid] = kbval;
    __syncthreads();
    floatx4 S[4];
#pragma unroll
    for (int nt = 0; nt < 4; ++nt) {
      S[nt] = (floatx4)(0.f);
#pragma unroll
      for (int ks = 0; ks < 2; ++ks) {
        short8v bk = *(const short8v*)&Ks[nt * 16 + t][ks * 32 + quad * 8];
        S[nt] = __builtin_amdgcn_mfma_f32_16x16x32_bf16(aq[ks], bk, S[nt], 0, 0, 0);
      }
    }
#pragma unroll
    for (int nt = 0; nt < 4; ++nt) {
      int bad = kbadS[nt * 16 + t];
#pragma unroll
      for (int r = 0; r < 4; ++r) {
        float p = exp2f((bad <= 0) ? S[nt][r] : -3.0e38f);
        ps[r] += p;
        Ps[16 * w + quad * 4 + r][((nt ^ quad) << 4) + t] = f2bu(p);
      }
    }
    short8v ap[2];
#pragma unroll
    for (int ks = 0; ks < 2; ++ks) {
      int chunk = (2 * ks + (quad >> 1)) ^ ((t >> 2) & 3);
      ap[ks] = *(const short8v*)&Ps[16 * w + t][(chunk << 4) + ((quad & 1) << 3)];
    }
#pragma unroll
    for (int dt = 0; dt < 4; ++dt)
#pragma unroll
      for (int ks = 0; ks < 2; ++ks) {
        short8v bv = *(const short8v*)&Vt[dt * 16 + t][ks * 32 + quad * 8];
        O[dt] = __builtin_amdgcn_mfma_f32_16x16x32_bf16(ap[ks], bv, O[dt], 0, 0, 0);
      }
  }
#pragma unroll
  for (int r = 0; r < 4; ++r)
#pragma unroll
    for (int off = 1; off < 16; off <<= 1) ps[r] += __shfl_xor(ps[r], off);
  float* pO = part + (size_t)bid * 4160;
#pragma unroll
  for (int dt = 0; dt < 4; ++dt)
#pragma unroll
    for (int r = 0; r < 4; ++r)
      pO[(16 * w + quad * 4 + r) * 64 + dt * 16 + t] = O[dt][r];
  if (t == 0)
#pragma unroll
    for (int r = 0; r < 4; ++r) pO[4096 + 16 * w + quad * 4 + r] = ps[r];
}

__global__ __launch_bounds__(256) void attn_comb(const float* __restrict__ part,
                                                 bf16* __restrict__ attnout) {
  int tid = threadIdx.x, lane = tid & 63, w = tid >> 6;
  int idx = blockIdx.x * 4 + w;  // [0, B*H*64)
  int bh = idx >> 6, row = idx & 63;
  int b = bh / HH, h = bh % HH;
  float o = 0.f, L = 0.f;
#pragma unroll
  for (int s16 = 0; s16 < 16; ++s16) {
    const float* p = part + (size_t)(bh * 16 + s16) * 4160;
    o += p[(row << 6) + lane];
    L += p[4096 + row];
  }
  attnout[((size_t)row * BB + b) * DD + h * 64 + lane] = __float2bfloat16(o / L);
}

extern "C" void kernel_launch(void* const* d_in, const int* in_sizes, int n_in,
                              void* d_out, int out_size, void* d_ws,
                              size_t ws_size, hipStream_t stream) {
  const int* kpm = (const int*)d_in[1];
  float* outp = (float*)d_out;
  const size_t SZ = (size_t)BB * HH * SS * 64;  // 6,291,456
  const size_t WSZ = (size_t)DD * DD;           // 589,824
  bf16* p = (bf16*)d_ws;
  bf16* cQ = p; p += SZ;        // canonical query
  bf16* cWt = p; p += 7 * WSZ;  // slots: q,k,v,kg,vg,qg,o
  bf16* cB = p; p += 7 * DD;
  bf16* q = p; p += SZ;   // heads [bh][s][d]   (gemm5c which=0..4 outputs
  bf16* k = p; p += SZ;   //  must stay contiguous in this order)
  bf16* v = p; p += SZ;   // TRANSPOSED [bh][d][s] (written by gemm5c)
  bf16* kg = p; p += SZ;  // heads
  bf16* vg = p; p += SZ;  // TRANSPOSED [bh][d][s] (written by gemm5c)
  bf16* qg = p; p += (size_t)BB * HH * GG * 64;
  bf16* attnout = p; p += SZ;
  float* part = (float*)p;  // 384 * 4160 floats
  int* flag = (int*)(part + (size_t)384 * 4160);
  dim3 blk(256);

  P7 wsrc{{d_in[2], d_in[4], d_in[6], d_in[10], d_in[12], d_in[8], d_in[14]}};
  P7 bsrc{{d_in[3], d_in[5], d_in[7], d_in[11], d_in[13], d_in[9], d_in[15]}};

  detect_dtype<<<1, blk, 0, stream>>>((const u16*)d_in[0], flag);
  prep<<<dim3(24, 24, 9), blk, 0, stream>>>(wsrc, bsrc, d_in[0], cWt, cB, cQ, flag);
  gemm5c<<<dim3(5 * 384 + 6), blk, 0, stream>>>(cQ, cWt, cB, q, qg);
  attn_local128<<<dim3(24 * 32), blk, 0, stream>>>(q, k, v, kpm, attnout);
  attn_glb<<<dim3(BB * HH * 16), blk, 0, stream>>>(qg, kg, vg, kpm, part);
  attn_comb<<<dim3(BB * HH * 16), blk, 0, stream>>>(part, attnout);
  gemm_out<<<dim3(64, 6), blk, 0, stream>>>(attnout, cWt + 6 * WSZ, cB + 6 * DD, outp);
}

// Round 10
// 270.515 us; speedup vs baseline: 1.0036x; 1.0036x over previous
//
#include <hip/hip_runtime.h>
#include <hip/hip_bf16.h>
#include <cstdint>

#define BB 2
#define SS 4096
#define DD 768
#define HH 12
#define GG 64
#define WW 256

typedef __hip_bfloat16 bf16;
typedef unsigned short u16;
typedef __attribute__((ext_vector_type(8))) short short8v;
typedef __attribute__((ext_vector_type(4))) float floatx4;
typedef __attribute__((ext_vector_type(16))) float floatx16;

// 0.125 * log2(e): softmax computed with exp2 (v_exp_f32 native)
#define QSCALE 0.18033688011112042f

__device__ __forceinline__ float b2f(u16 u) {
  return __uint_as_float(((unsigned int)u) << 16);
}
__device__ __forceinline__ u16 f2bu(float f) {
  bf16 h = __float2bfloat16(f);
  return *reinterpret_cast<u16*>(&h);
}
__device__ __forceinline__ void async_copy16(const u16* g, u16* l) {
  __builtin_amdgcn_global_load_lds(
      (const __attribute__((address_space(1))) void*)g,
      (__attribute__((address_space(3))) void*)l, 16, 0, 0);
}

struct P7 { const void* p[7]; };

// ---- dtype detect (inputs may be fp32 or bf16) ----
__global__ __launch_bounds__(256) void detect_dtype(const u16* __restrict__ q,
                                                    int* __restrict__ flag) {
  __shared__ int cnt;
  int tid = threadIdx.x;
  if (tid == 0) cnt = 0;
  __syncthreads();
  int bad = 0;
#pragma unroll
  for (int i = 0; i < 16; ++i) {
    float f = b2f(q[tid * 16 + i]);
    if (!isfinite(f) || fabsf(f) > 100.f) bad++;
  }
  atomicAdd(&cnt, bad);
  __syncthreads();
  if (tid == 0) *flag = (cnt > 256) ? 1 : 0;
}

// ---- fused prep: z<7 -> transpose W_z (32x32 tiles); z==7 -> canon query
// (vectorized x8); z==8 -> canon 7 biases. (round-6 verified)
__global__ __launch_bounds__(256) void prep(P7 wsrc, P7 bsrc,
                                            const void* __restrict__ qsrc,
                                            bf16* __restrict__ cWt,
                                            bf16* __restrict__ cB,
                                            bf16* __restrict__ cQ,
                                            const int* __restrict__ flag) {
  bool f32 = (*flag != 0);
  int z = blockIdx.z;
  if (z < 7) {
    __shared__ float tile[32][33];
    const void* src = wsrc.p[z];
    bf16* d = cWt + (size_t)z * DD * DD;
    int tx = threadIdx.x & 31, ty = threadIdx.x >> 5;
    int k0 = blockIdx.x * 32, n0 = blockIdx.y * 32;
#pragma unroll
    for (int i = 0; i < 32; i += 8) {
      int k = k0 + ty + i, n = n0 + tx;
      float v = f32 ? ((const float*)src)[(size_t)k * DD + n]
                    : b2f(((const u16*)src)[(size_t)k * DD + n]);
      tile[ty + i][tx] = v;
    }
    __syncthreads();
#pragma unroll
    for (int i = 0; i < 32; i += 8) {
      int n = n0 + ty + i, k = k0 + tx;
      d[(size_t)n * DD + k] = __float2bfloat16(tile[tx][ty + i]);
    }
  } else if (z == 7) {
    int bidx = blockIdx.x + 24 * blockIdx.y;  // 576 blocks
    const int nch = (BB * HH * SS * 64) / 8;  // 8-elem chunks
    u16* cQp = (u16*)cQ;
    for (int c = bidx * 256 + threadIdx.x; c < nch; c += 576 * 256) {
      int i = c * 8;
      if (f32) {
        const float* qs = (const float*)qsrc;
        float4 a = *(const float4*)(qs + i);
        float4 b = *(const float4*)(qs + i + 4);
        ushort4 o1 = make_ushort4(f2bu(a.x), f2bu(a.y), f2bu(a.z), f2bu(a.w));
        ushort4 o2 = make_ushort4(f2bu(b.x), f2bu(b.y), f2bu(b.z), f2bu(b.w));
        *(ushort4*)(cQp + i) = o1;
        *(ushort4*)(cQp + i + 4) = o2;
      } else {
        const u16* qs = (const u16*)qsrc;
        *(ushort4*)(cQp + i) = *(const ushort4*)(qs + i);
        *(ushort4*)(cQp + i + 4) = *(const ushort4*)(qs + i + 4);
      }
    }
  } else {
    int which = blockIdx.x;
    if (which >= 7 || blockIdx.y != 0) return;
    const void* s = bsrc.p[which];
    for (int j = threadIdx.x; j < DD; j += 256)
      cB[which * DD + j] =
          __float2bfloat16(f32 ? ((const float*)s)[j] : b2f(((const u16*)s)[j]));
  }
}

// XOR-swizzled [rows][64] LDS: logical chunk c of row r stored at c ^ (r&7).
// Fragment: rows base+(lane&31), k = kk + (lane>>5)*8 .. +7
__device__ __forceinline__ short8v lda(u16 (*Ls)[64], int base, int lane, int kk) {
  int row = base + (lane & 31);
  int c = (kk >> 3) + (lane >> 5);
  return *(const short8v*)&Ls[row][((c ^ (row & 7)) << 3)];
}

// ---- GEMM core v2 (128x128), single-buffered 2-barrier loop (m97 pattern) ----
__device__ __forceinline__ void gemm_core2(const u16* __restrict__ Xp,
                                           const u16* __restrict__ Wp, int bm,
                                           int bn, int tid, u16 (*As)[64],
                                           u16 (*Bs)[64], floatx16 (&acc)[2][2]) {
  int lane = tid & 63, w = tid >> 6;
  int wm = (w >> 1) * 64, wn = (w & 1) * 64;
  int r8 = lane >> 3;
  int sw = (((lane & 7) ^ (r8 & 7)) << 3);
  for (int k0 = 0; k0 < DD; k0 += 64) {
    __syncthreads();
#pragma unroll
    for (int j = 0; j < 4; ++j) {
      async_copy16(Wp + (size_t)(bn + w * 32 + j * 8 + r8) * DD + k0 + sw,
                   &As[w * 32 + j * 8][0]);
      async_copy16(Xp + (size_t)(bm + w * 32 + j * 8 + r8) * DD + k0 + sw,
                   &Bs[w * 32 + j * 8][0]);
    }
    __syncthreads();
#pragma unroll
    for (int kk = 0; kk < 64; kk += 16) {
      short8v a0 = lda(As, wn, lane, kk);
      short8v a1 = lda(As, wn + 32, lane, kk);
      short8v b0 = lda(Bs, wm, lane, kk);
      short8v b1 = lda(Bs, wm + 32, lane, kk);
      acc[0][0] = __builtin_amdgcn_mfma_f32_32x32x16_bf16(a0, b0, acc[0][0], 0, 0, 0);
      acc[0][1] = __builtin_amdgcn_mfma_f32_32x32x16_bf16(a0, b1, acc[0][1], 0, 0, 0);
      acc[1][0] = __builtin_amdgcn_mfma_f32_32x32x16_bf16(a1, b0, acc[1][0], 0, 0, 0);
      acc[1][1] = __builtin_amdgcn_mfma_f32_32x32x16_bf16(a1, b1, acc[1][1], 0, 0, 0);
    }
  }
}

// ---- Fused 6-projection GEMM, 128x128 tiles, XCD swizzle (round-3 verified).
// which in {2:v, 4:vg} writes TRANSPOSED [bh][d][s] directly (round-8
// verified); tr_vt2 deleted.
__global__ __launch_bounds__(256, 4) void gemm5c(const bf16* __restrict__ Xb,
                                                 const bf16* __restrict__ Wt0,
                                                 const bf16* __restrict__ bset,
                                                 bf16* __restrict__ out0,
                                                 bf16* __restrict__ qgp) {
  __shared__ __align__(16) u16 SH[16384];  // 32 KiB; reused by epilogues
  u16 (*As)[64] = (u16(*)[64])SH;
  u16 (*Bs)[64] = (u16(*)[64])(SH + 8192);
  int tid = threadIdx.x, lane = tid & 63, w = tid >> 6;
  // bijective chunked XCD swizzle over 1926 blocks
  int orig = blockIdx.x;
  const int NWG = 5 * 384 + 6, qq = NWG >> 3, rr = NWG & 7;  // 240, 6
  int xcd = orig & 7, idx = orig >> 3;
  int wg = (xcd < rr ? xcd * (qq + 1) : rr * (qq + 1) + (xcd - rr) * qq) + idx;
  int which, bm, bn;
  if (wg >= 1920) {
    which = 5; bm = 0; bn = (wg - 1920) * 128;
  } else {
    which = wg / 384;
    int rem = wg % 384;
    bm = (rem / 6) * 128;
    bn = (rem % 6) * 128;
  }
  const u16* Wp = (const u16*)Wt0 + (size_t)which * DD * DD;
  const u16* bias = (const u16*)bset + which * DD;
  int Sdim = (which == 5) ? GG : SS;
  u16* outp = (which == 5) ? (u16*)qgp
                           : (u16*)out0 + (size_t)which * BB * HH * SS * 64;
  float scale = (which == 0 || which == 5) ? QSCALE : 1.f;

  floatx16 acc[2][2];
#pragma unroll
  for (int i = 0; i < 2; ++i)
#pragma unroll
    for (int j = 0; j < 2; ++j) acc[i][j] = (floatx16)(0.f);
  gemm_core2((const u16*)Xb, Wp, bm, bn, tid, As, Bs, acc);

  if (which == 2 || which == 4) {
    // ---- transposed epilogue: out[(b*HH+h)*SS*64 + d*SS + s] ----
    const int TST = 132;
    u16* Ct = SH;  // [64][132] = 16896 B
    int h0 = bn >> 6;
    int wm = (w >> 1) * 64;
    int wnl = w & 1;  // ncol half owned by this wave
    int s0 = bm >> 1;
#pragma unroll
    for (int p = 0; p < 2; ++p) {   // head h0+p
      __syncthreads();  // prev-phase LDS reads complete
      if (wnl == p) {
#pragma unroll
        for (int nt = 0; nt < 2; ++nt)
#pragma unroll
          for (int mt = 0; mt < 2; ++mt)
#pragma unroll
            for (int g = 0; g < 4; ++g) {
              int ncl = nt * 32 + g * 8 + ((lane >> 5) << 2);  // d in [0,64)
              ushort4 bi = *(const ushort4*)&bias[bn + p * 64 + ncl];
              int mrow = wm + mt * 32 + (lane & 31);
              Ct[(ncl + 0) * TST + mrow] = f2bu(acc[nt][mt][4 * g + 0] + b2f(bi.x));
              Ct[(ncl + 1) * TST + mrow] = f2bu(acc[nt][mt][4 * g + 1] + b2f(bi.y));
              Ct[(ncl + 2) * TST + mrow] = f2bu(acc[nt][mt][4 * g + 2] + b2f(bi.z));
              Ct[(ncl + 3) * TST + mrow] = f2bu(acc[nt][mt][4 * g + 3] + b2f(bi.w));
            }
      }
      __syncthreads();
      // 2 b x 64 d x 8 chunks(8 s) = 1024 chunks / 256 threads
#pragma unroll
      for (int j = 0; j < 4; ++j) {
        int c = j * 256 + tid;
        int ch = c & 7, rrow = c >> 3;
        int d = rrow >> 1, b = rrow & 1;
        const u16* row = &Ct[d * TST + b];
        ushort4 o1, o2;
        o1.x = row[(ch * 8 + 0) << 1];
        o1.y = row[(ch * 8 + 1) << 1];
        o1.z = row[(ch * 8 + 2) << 1];
        o1.w = row[(ch * 8 + 3) << 1];
        o2.x = row[(ch * 8 + 4) << 1];
        o2.y = row[(ch * 8 + 5) << 1];
        o2.z = row[(ch * 8 + 6) << 1];
        o2.w = row[(ch * 8 + 7) << 1];
        u16* dst = outp + ((size_t)(b * HH + h0 + p)) * (SS * 64) +
                   (size_t)d * SS + s0 + ch * 8;
        *(ushort4*)dst = o1;
        *(ushort4*)(dst + 4) = o2;
      }
    }
    return;
  }

  // ---- heads-layout epilogue (which 0,1,3,5): 2 rounds via LDS ----
  const int CST = 132;  // u16 stride: 264B rows -> 2-way (free) bank pattern
  u16* Cs = SH;         // 64*132 = 8448 u16, fits in SH
  int wn = (w & 1) << 6, wmh = (w >> 1) << 5;
#pragma unroll
  for (int mt = 0; mt < 2; ++mt) {
    __syncthreads();  // prev-phase LDS reads complete
#pragma unroll
    for (int nt = 0; nt < 2; ++nt)
#pragma unroll
      for (int g = 0; g < 4; ++g) {
        int ncol = wn + nt * 32 + g * 8 + ((lane >> 5) << 2);
        ushort4 bi = *(const ushort4*)&bias[bn + ncol];
        int crow = wmh + (lane & 31);
        ushort4 o;
        o.x = f2bu((acc[nt][mt][4 * g + 0] + b2f(bi.x)) * scale);
        o.y = f2bu((acc[nt][mt][4 * g + 1] + b2f(bi.y)) * scale);
        o.z = f2bu((acc[nt][mt][4 * g + 2] + b2f(bi.z)) * scale);
        o.w = f2bu((acc[nt][mt][4 * g + 3] + b2f(bi.w)) * scale);
        *(ushort4*)&Cs[crow * CST + ncol] = o;
      }
    __syncthreads();
    // 64 m-rows x 2 heads x 16 chunks of 8B = 2048 chunks / 256 threads
#pragma unroll
    for (int j = 0; j < 8; ++j) {
      int c = j * 256 + tid;
      int ch = c & 15, mh = c >> 4;
      int mloc = mh >> 1, hloc = mh & 1;
      int m = bm + ((mloc >> 5) << 6) + mt * 32 + (mloc & 31);
      int s = m >> 1, b = m & 1;
      int h = (bn >> 6) + hloc;
      ushort4 vv = *(const ushort4*)&Cs[mloc * CST + hloc * 64 + ch * 4];
      *(ushort4*)(outp + ((size_t)(b * HH + h) * Sdim + s) * 64 + ch * 4) = vv;
    }
  }
}

// Output projection: fp32 flat out[m*768+n], 128x128 tiles.
// R6-verified coalesced epilogue; R10: flattened 1D grid (384 = 8*48) with
// chunked XCD swizzle — consecutive wg share the attnout m-panel, each XCD
// chunk keeps Wo (1.18 MB) + 8 m-panels L2-resident.
__global__ __launch_bounds__(256, 4) void gemm_out(const bf16* __restrict__ Xb,
                                                   const bf16* __restrict__ Wtb,
                                                   const bf16* __restrict__ biasb,
                                                   float* __restrict__ outv) {
  __shared__ __align__(16) u16 SH[16384];  // As/Bs in K-loop; Cf in epilogue
  u16 (*As)[64] = (u16(*)[64])SH;
  u16 (*Bs)[64] = (u16(*)[64])(SH + 8192);
  float* Cf = (float*)SH;  // [64][128] fp32, chunk-swizzled
  int tid = threadIdx.x, lane = tid & 63, w = tid >> 6;
  int wn = (w & 1) * 64;
  int orig = blockIdx.x;                      // 384 blocks, 384 % 8 == 0
  int wg = (orig & 7) * 48 + (orig >> 3);     // bijective chunked XCD swizzle
  int bm = (wg / 6) * 128, bn = (wg % 6) * 128;
  floatx16 acc[2][2];
#pragma unroll
  for (int i = 0; i < 2; ++i)
#pragma unroll
    for (int j = 0; j < 2; ++j) acc[i][j] = (floatx16)(0.f);
  gemm_core2((const u16*)Xb, (const u16*)Wtb, bm, bn, tid, As, Bs, acc);
  const u16* bias = (const u16*)biasb;
#pragma unroll
  for (int p = 0; p < 2; ++p) {
    __syncthreads();  // prev-phase LDS reads complete
    if ((w >> 1) == p) {
#pragma unroll
      for (int mt = 0; mt < 2; ++mt) {
        int mloc = mt * 32 + (lane & 31);
#pragma unroll
        for (int nt = 0; nt < 2; ++nt)
#pragma unroll
          for (int g = 0; g < 4; ++g) {
            int nl = wn + nt * 32 + g * 8 + ((lane >> 5) << 2);
            ushort4 bi = *(const ushort4*)&bias[bn + nl];
            float4 o;
            o.x = acc[nt][mt][4 * g + 0] + b2f(bi.x);
            o.y = acc[nt][mt][4 * g + 1] + b2f(bi.y);
            o.z = acc[nt][mt][4 * g + 2] + b2f(bi.z);
            o.w = acc[nt][mt][4 * g + 3] + b2f(bi.w);
            int n4 = nl >> 2;
            *(float4*)&Cf[mloc * 128 + ((n4 ^ (mloc & 31)) << 2)] = o;
          }
      }
    }
    __syncthreads();
    // 64 m-rows x 32 chunks of 16B = 2048 chunks / 256 threads
#pragma unroll
    for (int j = 0; j < 8; ++j) {
      int c = j * 256 + tid;
      int mloc = c >> 5, nch = c & 31;
      float4 v = *(const float4*)&Cf[mloc * 128 + ((nch ^ (mloc & 31)) << 2)];
      *(float4*)(outv + (size_t)(bm + p * 64 + mloc) * DD + bn + nch * 4) = v;
    }
  }
}

// ---- MFMA flash attention, 128-row Q tiles, async staging, swapped PV ----
// q pre-scaled by 0.125*log2(e): probabilities via exp2f.
// R10: PQ alias kept (LDS 34.75 KiB) but launch_bounds back to (256,3) —
// R9's regression matched the R5 signature: min-waves=4 caps VGPR at 128 and
// spills. With (256,3) the allocator is unconstrained; if natural VGPR <= 128
// the HW still fits 4 blocks/CU (LDS no longer caps), else behaves as R8.
__global__ __launch_bounds__(256, 3) void attn_local128(
    const bf16* __restrict__ qb, const bf16* __restrict__ kb,
    const bf16* __restrict__ vtb, const int* __restrict__ kpm,
    bf16* __restrict__ attnout) {
  __shared__ __align__(16) u16 PQ[128 * 72];  // Ps[128][72]; Qs[128][64] alias
  __shared__ __align__(16) u16 Ks[64][64];
  __shared__ __align__(16) u16 Vt[64][64];  // [d][key]
  __shared__ float Ls[128];
  __shared__ int kbadS[64];
  int bid = blockIdx.x;
  int tile = bid & 31, bh = bid >> 5;
  int b = bh / HH, h = bh % HH;
  int tid = threadIdx.x, lane = tid & 63, w = tid >> 6;
  int quad = lane >> 4, t = lane & 15;
  const u16* qp = (const u16*)qb + (size_t)bh * SS * 64;
  const u16* kp = (const u16*)kb + (size_t)bh * SS * 64;
  const u16* vp = (const u16*)vtb + (size_t)bh * SS * 64;  // rows are d
  int sq0 = GG + tile * 128;
#pragma unroll
  for (int j = 0; j < 4; ++j) {
    int qr = sq0 + w * 32 + j * 8 + (lane >> 3);
    int sr = qr < SS ? qr : SS - 1;
    async_copy16(qp + (size_t)sr * 64 + (lane & 7) * 8, &PQ[(w * 32 + j * 8) * 64]);
  }
  __syncthreads();
  short8v aq[2][2];
#pragma unroll
  for (int st = 0; st < 2; ++st)
#pragma unroll
    for (int ks = 0; ks < 2; ++ks)
      aq[st][ks] =
          *(const short8v*)&PQ[(w * 32 + st * 16 + t) * 64 + ks * 32 + quad * 8];
  floatx4 O[2][4];
#pragma unroll
  for (int st = 0; st < 2; ++st)
#pragma unroll
    for (int dt = 0; dt < 4; ++dt) O[st][dt] = (floatx4)(0.f);
  float ps[2][4] = {};
  int win_lo = max(sq0 - WW, GG);
  int win_hi = min(sq0 + 127 + WW, SS - 1);
  int kb_lo = win_lo & ~63;
  int iters = ((win_hi - kb_lo) >> 6) + 2;  // +1: global-keys block
  for (int it = 0; it < iters; ++it) {
    int kbs = (it == 0) ? 0 : kb_lo + ((it - 1) << 6);
    __syncthreads();  // also fences aq ds_reads (lgkm drained at barrier)
#pragma unroll
    for (int j = 0; j < 2; ++j) {
      async_copy16(kp + (size_t)(kbs + w * 16 + j * 8 + (lane >> 3)) * 64 +
                       (lane & 7) * 8,
                   &Ks[w * 16 + j * 8][0]);
      async_copy16(vp + (size_t)(w * 16 + j * 8 + (lane >> 3)) * SS + kbs +
                       (lane & 7) * 8,
                   &Vt[w * 16 + j * 8][0]);
    }
    if (tid < 64) kbadS[tid] = kpm[b * SS + kbs + tid];
    __syncthreads();
#pragma unroll
    for (int st = 0; st < 2; ++st) {
      floatx4 S[4];
#pragma unroll
      for (int nt = 0; nt < 4; ++nt) {
        S[nt] = (floatx4)(0.f);
#pragma unroll
        for (int ks = 0; ks < 2; ++ks) {
          short8v bk = *(const short8v*)&Ks[nt * 16 + t][ks * 32 + quad * 8];
          S[nt] = __builtin_amdgcn_mfma_f32_16x16x32_bf16(aq[st][ks], bk, S[nt],
                                                          0, 0, 0);
        }
      }
      int prow = w * 32 + st * 16 + quad * 4;
      if (it == 0) {
#pragma unroll
        for (int nt = 0; nt < 4; ++nt)
#pragma unroll
          for (int r = 0; r < 4; ++r) {
            float p = exp2f(S[nt][r]);
            ps[st][r] += p;
            PQ[(prow + r) * 72 + (((nt ^ quad) << 4) + t)] = f2bu(p);
          }
      } else {
#pragma unroll
        for (int r = 0; r < 4; ++r) {
          int qr = sq0 + prow + r;
          int off = kbs + t + WW - qr;
#pragma unroll
          for (int nt = 0; nt < 4; ++nt) {
            int bad = kbadS[nt * 16 + t];
            unsigned u = (unsigned)(off + nt * 16);
            float p = exp2f((u <= 2 * WW && bad == 0) ? S[nt][r] : -3.0e38f);
            ps[st][r] += p;
            PQ[(prow + r) * 72 + (((nt ^ quad) << 4) + t)] = f2bu(p);
          }
        }
      }
    }
    short8v ap[2][2];
#pragma unroll
    for (int st = 0; st < 2; ++st)
#pragma unroll
      for (int ks = 0; ks < 2; ++ks) {
        int chunk = (2 * ks + (quad >> 1)) ^ ((t >> 2) & 3);
        ap[st][ks] = *(const short8v*)&PQ[(w * 32 + st * 16 + t) * 72 +
                                          ((chunk << 4) + ((quad & 1) << 3))];
      }
#pragma unroll
    for (int dt = 0; dt < 4; ++dt) {
#pragma unroll
      for (int ks = 0; ks < 2; ++ks) {
        short8v av = *(const short8v*)&Vt[dt * 16 + t][ks * 32 + quad * 8];
#pragma unroll
        for (int st = 0; st < 2; ++st)
          O[st][dt] = __builtin_amdgcn_mfma_f32_16x16x32_bf16(av, ap[st][ks],
                                                              O[st][dt], 0, 0, 0);
      }
    }
  }
#pragma unroll
  for (int st = 0; st < 2; ++st) {
#pragma unroll
    for (int r = 0; r < 4; ++r)
#pragma unroll
      for (int off = 1; off < 16; off <<= 1) ps[st][r] += __shfl_xor(ps[st][r], off);
    if (t == 0)
#pragma unroll
      for (int r = 0; r < 4; ++r) Ls[w * 32 + st * 16 + quad * 4 + r] = ps[st][r];
  }
#pragma unroll
  for (int st = 0; st < 2; ++st) {
    int q = sq0 + w * 32 + st * 16 + t;
    if (q < SS) {
      float linv = 1.0f / Ls[w * 32 + st * 16 + t];
#pragma unroll
      for (int dt = 0; dt < 4; ++dt) {
        ushort4 o;
        o.x = f2bu(O[st][dt][0] * linv);
        o.y = f2bu(O[st][dt][1] * linv);
        o.z = f2bu(O[st][dt][2] * linv);
        o.w = f2bu(O[st][dt][3] * linv);
        *(ushort4*)((u16*)attnout + ((size_t)q * BB + b) * DD + h * 64 +
                    dt * 16 + quad * 4) = o;
      }
    }
  }
}

// Global-row attention (rows < G), 256-key segment per block; fp32 partials.
__global__ __launch_bounds__(256) void attn_glb(
    const bf16* __restrict__ qgb, const bf16* __restrict__ kgb,
    const bf16* __restrict__ vtb, const int* __restrict__ kpm,
    float* __restrict__ part) {
  __shared__ __align__(16) u16 Qs[64][72];
  __shared__ __align__(16) u16 Ks[64][72];
  __shared__ __align__(16) u16 Vt[64][72];
  __shared__ __align__(16) u16 Ps[64][72];
  __shared__ int kbadS[64];
  int bid = blockIdx.x;
  int bh = bid >> 4, seg = bid & 15;
  int b = bh / HH;
  int tid = threadIdx.x, lane = tid & 63, w = tid >> 6;
  int quad = lane >> 4, t = lane & 15;
  const u16* qp = (const u16*)qgb + (size_t)bh * GG * 64;
  const u16* kp = (const u16*)kgb + (size_t)bh * SS * 64;
  const u16* vp = (const u16*)vtb + (size_t)bh * SS * 64;  // rows are d
  int srow = tid >> 2, scol = (tid & 3) * 16;
#pragma unroll
  for (int i = 0; i < 4; ++i)
    *(ushort4*)&Qs[srow][scol + 4 * i] =
        *(const ushort4*)(qp + (size_t)srow * 64 + scol + 4 * i);
  __syncthreads();
  short8v aq[2];
#pragma unroll
  for (int ks = 0; ks < 2; ++ks)
    aq[ks] = *(const short8v*)&Qs[16 * w + t][ks * 32 + quad * 8];
  floatx4 O[4];
#pragma unroll
  for (int i = 0; i < 4; ++i) O[i] = (floatx4)(0.f);
  float ps[4] = {0.f, 0.f, 0.f, 0.f};
  for (int it = 0; it < 4; ++it) {
    int kbs = (seg << 8) + (it << 6);
    ushort4 ku[4], vu[4];
#pragma unroll
    for (int i = 0; i < 4; ++i) {
      ku[i] = *(const ushort4*)(kp + (size_t)(kbs + srow) * 64 + scol + 4 * i);
      vu[i] = *(const ushort4*)(vp + (size_t)srow * SS + kbs + scol + 4 * i);
    }
    int kbval = (tid < 64) ? kpm[b * SS + kbs + tid] : 0;
    __syncthreads();
#pragma unroll
    for (int i = 0; i < 4; ++i) {
      *(ushort4*)&Ks[srow][scol + 4 * i] = ku[i];
      *(ushort4*)&Vt[srow][scol + 4 * i] = vu[i];
    }
    if (tid < 64) kbadS[tid] = kbval;
    __syncthreads();
    floatx4 S[4];
#pragma unroll
    for (int nt = 0; nt < 4; ++nt) {
      S[nt] = (floatx4)(0.f);
#pragma unroll
      for (int ks = 0; ks < 2; ++ks) {
        short8v bk = *(const short8v*)&Ks[nt * 16 + t][ks * 32 + quad * 8];
        S[nt] = __builtin_amdgcn_mfma_f32_16x16x32_bf16(aq[ks], bk, S[nt], 0, 0, 0);
      }
    }
#pragma unroll
    for (int nt = 0; nt < 4; ++nt) {
      int bad = kbadS[nt * 16 + t];
#pragma unroll
      for (int r = 0; r < 4; ++r) {
        float p = exp2f((bad <= 0) ? S[nt][r] : -3.0e38f);
        ps[r] += p;
        Ps[16 * w + quad * 4 + r][((nt ^ quad) << 4) + t] = f2bu(p);
      }
    }
    short8v ap[2];
#pragma unroll
    for (int ks = 0; ks < 2; ++ks) {
      int chunk = (2 * ks + (quad >> 1)) ^ ((t >> 2) & 3);
      ap[ks] = *(const short8v*)&Ps[16 * w + t][(chunk << 4) + ((quad & 1) << 3)];
    }
#pragma unroll
    for (int dt = 0; dt < 4; ++dt)
#pragma unroll
      for (int ks = 0; ks < 2; ++ks) {
        short8v bv = *(const short8v*)&Vt[dt * 16 + t][ks * 32 + quad * 8];
        O[dt] = __builtin_amdgcn_mfma_f32_16x16x32_bf16(ap[ks], bv, O[dt], 0, 0, 0);
      }
  }
#pragma unroll
  for (int r = 0; r < 4; ++r)
#pragma unroll
    for (int off = 1; off < 16; off <<= 1) ps[r] += __shfl_xor(ps[r], off);
  float* pO = part + (size_t)bid * 4160;
#pragma unroll
  for (int dt = 0; dt < 4; ++dt)
#pragma unroll
    for (int r = 0; r < 4; ++r)
      pO[(16 * w + quad * 4 + r) * 64 + dt * 16 + t] = O[dt][r];
  if (t == 0)
#pragma unroll
    for (int r = 0; r < 4; ++r) pO[4096 + 16 * w + quad * 4 + r] = ps[r];
}

__global__ __launch_bounds__(256) void attn_comb(const float* __restrict__ part,
                                                 bf16* __restrict__ attnout) {
  int tid = threadIdx.x, lane = tid & 63, w = tid >> 6;
  int idx = blockIdx.x * 4 + w;  // [0, B*H*64)
  int bh = idx >> 6, row = idx & 63;
  int b = bh / HH, h = bh % HH;
  float o = 0.f, L = 0.f;
#pragma unroll
  for (int s16 = 0; s16 < 16; ++s16) {
    const float* p = part + (size_t)(bh * 16 + s16) * 4160;
    o += p[(row << 6) + lane];
    L += p[4096 + row];
  }
  attnout[((size_t)row * BB + b) * DD + h * 64 + lane] = __float2bfloat16(o / L);
}

extern "C" void kernel_launch(void* const* d_in, const int* in_sizes, int n_in,
                              void* d_out, int out_size, void* d_ws,
                              size_t ws_size, hipStream_t stream) {
  const int* kpm = (const int*)d_in[1];
  float* outp = (float*)d_out;
  const size_t SZ = (size_t)BB * HH * SS * 64;  // 6,291,456
  const size_t WSZ = (size_t)DD * DD;           // 589,824
  bf16* p = (bf16*)d_ws;
  bf16* cQ = p; p += SZ;        // canonical query
  bf16* cWt = p; p += 7 * WSZ;  // slots: q,k,v,kg,vg,qg,o
  bf16* cB = p; p += 7 * DD;
  bf16* q = p; p += SZ;   // heads [bh][s][d]   (gemm5c which=0..4 outputs
  bf16* k = p; p += SZ;   //  must stay contiguous in this order)
  bf16* v = p; p += SZ;   // TRANSPOSED [bh][d][s] (written by gemm5c)
  bf16* kg = p; p += SZ;  // heads
  bf16* vg = p; p += SZ;  // TRANSPOSED [bh][d][s] (written by gemm5c)
  bf16* qg = p; p += (size_t)BB * HH * GG * 64;
  bf16* attnout = p; p += SZ;
  float* part = (float*)p;  // 384 * 4160 floats
  int* flag = (int*)(part + (size_t)384 * 4160);
  dim3 blk(256);

  P7 wsrc{{d_in[2], d_in[4], d_in[6], d_in[10], d_in[12], d_in[8], d_in[14]}};
  P7 bsrc{{d_in[3], d_in[5], d_in[7], d_in[11], d_in[13], d_in[9], d_in[15]}};

  detect_dtype<<<1, blk, 0, stream>>>((const u16*)d_in[0], flag);
  prep<<<dim3(24, 24, 9), blk, 0, stream>>>(wsrc, bsrc, d_in[0], cWt, cB, cQ, flag);
  gemm5c<<<dim3(5 * 384 + 6), blk, 0, stream>>>(cQ, cWt, cB, q, qg);
  attn_local128<<<dim3(24 * 32), blk, 0, stream>>>(q, k, v, kpm, attnout);
  attn_glb<<<dim3(BB * HH * 16), blk, 0, stream>>>(qg, kg, vg, kpm, part);
  attn_comb<<<dim3(BB * HH * 16), blk, 0, stream>>>(part, attnout);
  gemm_out<<<dim3(384), blk, 0, stream>>>(attnout, cWt + 6 * WSZ, cB + 6 * DD, outp);
}

// Round 11
// 259.111 us; speedup vs baseline: 1.0478x; 1.0440x over previous
//
#include <hip/hip_runtime.h>
#include <hip/hip_bf16.h>
#include <cstdint>

#define BB 2
#define SS 4096
#define DD 768
#define HH 12
#define GG 64
#define WW 256

typedef __hip_bfloat16 bf16;
typedef unsigned short u16;
typedef __attribute__((ext_vector_type(8))) short short8v;
typedef __attribute__((ext_vector_type(4))) float floatx4;
typedef __attribute__((ext_vector_type(16))) float floatx16;

// 0.125 * log2(e): softmax computed with exp2 (v_exp_f32 native)
#define QSCALE 0.18033688011112042f

__device__ __forceinline__ float b2f(u16 u) {
  return __uint_as_float(((unsigned int)u) << 16);
}
__device__ __forceinline__ u16 f2bu(float f) {
  bf16 h = __float2bfloat16(f);
  return *reinterpret_cast<u16*>(&h);
}
__device__ __forceinline__ void async_copy16(const u16* g, u16* l) {
  __builtin_amdgcn_global_load_lds(
      (const __attribute__((address_space(1))) void*)g,
      (__attribute__((address_space(3))) void*)l, 16, 0, 0);
}

struct P7 { const void* p[7]; };

// ---- dtype detect (inputs may be fp32 or bf16) ----
__global__ __launch_bounds__(256) void detect_dtype(const u16* __restrict__ q,
                                                    int* __restrict__ flag) {
  __shared__ int cnt;
  int tid = threadIdx.x;
  if (tid == 0) cnt = 0;
  __syncthreads();
  int bad = 0;
#pragma unroll
  for (int i = 0; i < 16; ++i) {
    float f = b2f(q[tid * 16 + i]);
    if (!isfinite(f) || fabsf(f) > 100.f) bad++;
  }
  atomicAdd(&cnt, bad);
  __syncthreads();
  if (tid == 0) *flag = (cnt > 256) ? 1 : 0;
}

// ---- fused prep: z<7 -> transpose W_z (32x32 tiles); z==7 -> canon query
// (vectorized x8); z==8 -> canon 7 biases. (round-6 verified)
__global__ __launch_bounds__(256) void prep(P7 wsrc, P7 bsrc,
                                            const void* __restrict__ qsrc,
                                            bf16* __restrict__ cWt,
                                            bf16* __restrict__ cB,
                                            bf16* __restrict__ cQ,
                                            const int* __restrict__ flag) {
  bool f32 = (*flag != 0);
  int z = blockIdx.z;
  if (z < 7) {
    __shared__ float tile[32][33];
    const void* src = wsrc.p[z];
    bf16* d = cWt + (size_t)z * DD * DD;
    int tx = threadIdx.x & 31, ty = threadIdx.x >> 5;
    int k0 = blockIdx.x * 32, n0 = blockIdx.y * 32;
#pragma unroll
    for (int i = 0; i < 32; i += 8) {
      int k = k0 + ty + i, n = n0 + tx;
      float v = f32 ? ((const float*)src)[(size_t)k * DD + n]
                    : b2f(((const u16*)src)[(size_t)k * DD + n]);
      tile[ty + i][tx] = v;
    }
    __syncthreads();
#pragma unroll
    for (int i = 0; i < 32; i += 8) {
      int n = n0 + ty + i, k = k0 + tx;
      d[(size_t)n * DD + k] = __float2bfloat16(tile[tx][ty + i]);
    }
  } else if (z == 7) {
    int bidx = blockIdx.x + 24 * blockIdx.y;  // 576 blocks
    const int nch = (BB * HH * SS * 64) / 8;  // 8-elem chunks
    u16* cQp = (u16*)cQ;
    for (int c = bidx * 256 + threadIdx.x; c < nch; c += 576 * 256) {
      int i = c * 8;
      if (f32) {
        const float* qs = (const float*)qsrc;
        float4 a = *(const float4*)(qs + i);
        float4 b = *(const float4*)(qs + i + 4);
        ushort4 o1 = make_ushort4(f2bu(a.x), f2bu(a.y), f2bu(a.z), f2bu(a.w));
        ushort4 o2 = make_ushort4(f2bu(b.x), f2bu(b.y), f2bu(b.z), f2bu(b.w));
        *(ushort4*)(cQp + i) = o1;
        *(ushort4*)(cQp + i + 4) = o2;
      } else {
        const u16* qs = (const u16*)qsrc;
        *(ushort4*)(cQp + i) = *(const ushort4*)(qs + i);
        *(ushort4*)(cQp + i + 4) = *(const ushort4*)(qs + i + 4);
      }
    }
  } else {
    int which = blockIdx.x;
    if (which >= 7 || blockIdx.y != 0) return;
    const void* s = bsrc.p[which];
    for (int j = threadIdx.x; j < DD; j += 256)
      cB[which * DD + j] =
          __float2bfloat16(f32 ? ((const float*)s)[j] : b2f(((const u16*)s)[j]));
  }
}

// XOR-swizzled [rows][64] LDS: logical chunk c of row r stored at c ^ (r&7).
// Fragment: rows base+(lane&31), k = kk + (lane>>5)*8 .. +7
__device__ __forceinline__ short8v lda(u16 (*Ls)[64], int base, int lane, int kk) {
  int row = base + (lane & 31);
  int c = (kk >> 3) + (lane >> 5);
  return *(const short8v*)&Ls[row][((c ^ (row & 7)) << 3)];
}

// ---- GEMM core v2 (128x128), single-buffered 2-barrier loop (m97 pattern) ----
__device__ __forceinline__ void gemm_core2(const u16* __restrict__ Xp,
                                           const u16* __restrict__ Wp, int bm,
                                           int bn, int tid, u16 (*As)[64],
                                           u16 (*Bs)[64], floatx16 (&acc)[2][2]) {
  int lane = tid & 63, w = tid >> 6;
  int wm = (w >> 1) * 64, wn = (w & 1) * 64;
  int r8 = lane >> 3;
  int sw = (((lane & 7) ^ (r8 & 7)) << 3);
  for (int k0 = 0; k0 < DD; k0 += 64) {
    __syncthreads();
#pragma unroll
    for (int j = 0; j < 4; ++j) {
      async_copy16(Wp + (size_t)(bn + w * 32 + j * 8 + r8) * DD + k0 + sw,
                   &As[w * 32 + j * 8][0]);
      async_copy16(Xp + (size_t)(bm + w * 32 + j * 8 + r8) * DD + k0 + sw,
                   &Bs[w * 32 + j * 8][0]);
    }
    __syncthreads();
#pragma unroll
    for (int kk = 0; kk < 64; kk += 16) {
      short8v a0 = lda(As, wn, lane, kk);
      short8v a1 = lda(As, wn + 32, lane, kk);
      short8v b0 = lda(Bs, wm, lane, kk);
      short8v b1 = lda(Bs, wm + 32, lane, kk);
      acc[0][0] = __builtin_amdgcn_mfma_f32_32x32x16_bf16(a0, b0, acc[0][0], 0, 0, 0);
      acc[0][1] = __builtin_amdgcn_mfma_f32_32x32x16_bf16(a0, b1, acc[0][1], 0, 0, 0);
      acc[1][0] = __builtin_amdgcn_mfma_f32_32x32x16_bf16(a1, b0, acc[1][0], 0, 0, 0);
      acc[1][1] = __builtin_amdgcn_mfma_f32_32x32x16_bf16(a1, b1, acc[1][1], 0, 0, 0);
    }
  }
}

// ---- Fused 6-projection GEMM, 128x128 tiles, XCD swizzle (round-3 verified).
// which in {2:v, 4:vg} writes TRANSPOSED [bh][d][s] directly (round-8
// verified); tr_vt2 deleted.
__global__ __launch_bounds__(256, 4) void gemm5c(const bf16* __restrict__ Xb,
                                                 const bf16* __restrict__ Wt0,
                                                 const bf16* __restrict__ bset,
                                                 bf16* __restrict__ out0,
                                                 bf16* __restrict__ qgp) {
  __shared__ __align__(16) u16 SH[16384];  // 32 KiB; reused by epilogues
  u16 (*As)[64] = (u16(*)[64])SH;
  u16 (*Bs)[64] = (u16(*)[64])(SH + 8192);
  int tid = threadIdx.x, lane = tid & 63, w = tid >> 6;
  // bijective chunked XCD swizzle over 1926 blocks
  int orig = blockIdx.x;
  const int NWG = 5 * 384 + 6, qq = NWG >> 3, rr = NWG & 7;  // 240, 6
  int xcd = orig & 7, idx = orig >> 3;
  int wg = (xcd < rr ? xcd * (qq + 1) : rr * (qq + 1) + (xcd - rr) * qq) + idx;
  int which, bm, bn;
  if (wg >= 1920) {
    which = 5; bm = 0; bn = (wg - 1920) * 128;
  } else {
    which = wg / 384;
    int rem = wg % 384;
    bm = (rem / 6) * 128;
    bn = (rem % 6) * 128;
  }
  const u16* Wp = (const u16*)Wt0 + (size_t)which * DD * DD;
  const u16* bias = (const u16*)bset + which * DD;
  int Sdim = (which == 5) ? GG : SS;
  u16* outp = (which == 5) ? (u16*)qgp
                           : (u16*)out0 + (size_t)which * BB * HH * SS * 64;
  float scale = (which == 0 || which == 5) ? QSCALE : 1.f;

  floatx16 acc[2][2];
#pragma unroll
  for (int i = 0; i < 2; ++i)
#pragma unroll
    for (int j = 0; j < 2; ++j) acc[i][j] = (floatx16)(0.f);
  gemm_core2((const u16*)Xb, Wp, bm, bn, tid, As, Bs, acc);

  if (which == 2 || which == 4) {
    // ---- transposed epilogue: out[(b*HH+h)*SS*64 + d*SS + s] ----
    const int TST = 132;
    u16* Ct = SH;  // [64][132] = 16896 B
    int h0 = bn >> 6;
    int wm = (w >> 1) * 64;
    int wnl = w & 1;  // ncol half owned by this wave
    int s0 = bm >> 1;
#pragma unroll
    for (int p = 0; p < 2; ++p) {   // head h0+p
      __syncthreads();  // prev-phase LDS reads complete
      if (wnl == p) {
#pragma unroll
        for (int nt = 0; nt < 2; ++nt)
#pragma unroll
          for (int mt = 0; mt < 2; ++mt)
#pragma unroll
            for (int g = 0; g < 4; ++g) {
              int ncl = nt * 32 + g * 8 + ((lane >> 5) << 2);  // d in [0,64)
              ushort4 bi = *(const ushort4*)&bias[bn + p * 64 + ncl];
              int mrow = wm + mt * 32 + (lane & 31);
              Ct[(ncl + 0) * TST + mrow] = f2bu(acc[nt][mt][4 * g + 0] + b2f(bi.x));
              Ct[(ncl + 1) * TST + mrow] = f2bu(acc[nt][mt][4 * g + 1] + b2f(bi.y));
              Ct[(ncl + 2) * TST + mrow] = f2bu(acc[nt][mt][4 * g + 2] + b2f(bi.z));
              Ct[(ncl + 3) * TST + mrow] = f2bu(acc[nt][mt][4 * g + 3] + b2f(bi.w));
            }
      }
      __syncthreads();
      // 2 b x 64 d x 8 chunks(8 s) = 1024 chunks / 256 threads
#pragma unroll
      for (int j = 0; j < 4; ++j) {
        int c = j * 256 + tid;
        int ch = c & 7, rrow = c >> 3;
        int d = rrow >> 1, b = rrow & 1;
        const u16* row = &Ct[d * TST + b];
        ushort4 o1, o2;
        o1.x = row[(ch * 8 + 0) << 1];
        o1.y = row[(ch * 8 + 1) << 1];
        o1.z = row[(ch * 8 + 2) << 1];
        o1.w = row[(ch * 8 + 3) << 1];
        o2.x = row[(ch * 8 + 4) << 1];
        o2.y = row[(ch * 8 + 5) << 1];
        o2.z = row[(ch * 8 + 6) << 1];
        o2.w = row[(ch * 8 + 7) << 1];
        u16* dst = outp + ((size_t)(b * HH + h0 + p)) * (SS * 64) +
                   (size_t)d * SS + s0 + ch * 8;
        *(ushort4*)dst = o1;
        *(ushort4*)(dst + 4) = o2;
      }
    }
    return;
  }

  // ---- heads-layout epilogue (which 0,1,3,5): 2 rounds via LDS ----
  const int CST = 132;  // u16 stride: 264B rows -> 2-way (free) bank pattern
  u16* Cs = SH;         // 64*132 = 8448 u16, fits in SH
  int wn = (w & 1) << 6, wmh = (w >> 1) << 5;
#pragma unroll
  for (int mt = 0; mt < 2; ++mt) {
    __syncthreads();  // prev-phase LDS reads complete
#pragma unroll
    for (int nt = 0; nt < 2; ++nt)
#pragma unroll
      for (int g = 0; g < 4; ++g) {
        int ncol = wn + nt * 32 + g * 8 + ((lane >> 5) << 2);
        ushort4 bi = *(const ushort4*)&bias[bn + ncol];
        int crow = wmh + (lane & 31);
        ushort4 o;
        o.x = f2bu((acc[nt][mt][4 * g + 0] + b2f(bi.x)) * scale);
        o.y = f2bu((acc[nt][mt][4 * g + 1] + b2f(bi.y)) * scale);
        o.z = f2bu((acc[nt][mt][4 * g + 2] + b2f(bi.z)) * scale);
        o.w = f2bu((acc[nt][mt][4 * g + 3] + b2f(bi.w)) * scale);
        *(ushort4*)&Cs[crow * CST + ncol] = o;
      }
    __syncthreads();
    // 64 m-rows x 2 heads x 16 chunks of 8B = 2048 chunks / 256 threads
#pragma unroll
    for (int j = 0; j < 8; ++j) {
      int c = j * 256 + tid;
      int ch = c & 15, mh = c >> 4;
      int mloc = mh >> 1, hloc = mh & 1;
      int m = bm + ((mloc >> 5) << 6) + mt * 32 + (mloc & 31);
      int s = m >> 1, b = m & 1;
      int h = (bn >> 6) + hloc;
      ushort4 vv = *(const ushort4*)&Cs[mloc * CST + hloc * 64 + ch * 4];
      *(ushort4*)(outp + ((size_t)(b * HH + h) * Sdim + s) * 64 + ch * 4) = vv;
    }
  }
}

// Output projection: fp32 flat out[m*768+n], 128x128 tiles.
// R6-verified coalesced epilogue; R10-verified 1D grid (384 = 8*48) with
// chunked XCD swizzle.
__global__ __launch_bounds__(256, 4) void gemm_out(const bf16* __restrict__ Xb,
                                                   const bf16* __restrict__ Wtb,
                                                   const bf16* __restrict__ biasb,
                                                   float* __restrict__ outv) {
  __shared__ __align__(16) u16 SH[16384];  // As/Bs in K-loop; Cf in epilogue
  u16 (*As)[64] = (u16(*)[64])SH;
  u16 (*Bs)[64] = (u16(*)[64])(SH + 8192);
  float* Cf = (float*)SH;  // [64][128] fp32, chunk-swizzled
  int tid = threadIdx.x, lane = tid & 63, w = tid >> 6;
  int wn = (w & 1) * 64;
  int orig = blockIdx.x;                      // 384 blocks, 384 % 8 == 0
  int wg = (orig & 7) * 48 + (orig >> 3);     // bijective chunked XCD swizzle
  int bm = (wg / 6) * 128, bn = (wg % 6) * 128;
  floatx16 acc[2][2];
#pragma unroll
  for (int i = 0; i < 2; ++i)
#pragma unroll
    for (int j = 0; j < 2; ++j) acc[i][j] = (floatx16)(0.f);
  gemm_core2((const u16*)Xb, (const u16*)Wtb, bm, bn, tid, As, Bs, acc);
  const u16* bias = (const u16*)biasb;
#pragma unroll
  for (int p = 0; p < 2; ++p) {
    __syncthreads();  // prev-phase LDS reads complete
    if ((w >> 1) == p) {
#pragma unroll
      for (int mt = 0; mt < 2; ++mt) {
        int mloc = mt * 32 + (lane & 31);
#pragma unroll
        for (int nt = 0; nt < 2; ++nt)
#pragma unroll
          for (int g = 0; g < 4; ++g) {
            int nl = wn + nt * 32 + g * 8 + ((lane >> 5) << 2);
            ushort4 bi = *(const ushort4*)&bias[bn + nl];
            float4 o;
            o.x = acc[nt][mt][4 * g + 0] + b2f(bi.x);
            o.y = acc[nt][mt][4 * g + 1] + b2f(bi.y);
            o.z = acc[nt][mt][4 * g + 2] + b2f(bi.z);
            o.w = acc[nt][mt][4 * g + 3] + b2f(bi.w);
            int n4 = nl >> 2;
            *(float4*)&Cf[mloc * 128 + ((n4 ^ (mloc & 31)) << 2)] = o;
          }
      }
    }
    __syncthreads();
    // 64 m-rows x 32 chunks of 16B = 2048 chunks / 256 threads
#pragma unroll
    for (int j = 0; j < 8; ++j) {
      int c = j * 256 + tid;
      int mloc = c >> 5, nch = c & 31;
      float4 v = *(const float4*)&Cf[mloc * 128 + ((nch ^ (mloc & 31)) << 2)];
      *(float4*)(outv + (size_t)(bm + p * 64 + mloc) * DD + bn + nch * 4) = v;
    }
  }
}

// ---- MFMA flash attention, 128-row Q tiles, async staging, swapped PV ----
// q pre-scaled by 0.125*log2(e): probabilities via exp2f.
// ROUND-8 VERIFIED version restored exactly: separate Qs+Ps, 50.7 KiB LDS,
// 3 blocks/CU (empirically optimal; every 4-blocks/CU variant lost ~8 us:
// R5, R9, R10).
__global__ __launch_bounds__(256, 3) void attn_local128(
    const bf16* __restrict__ qb, const bf16* __restrict__ kb,
    const bf16* __restrict__ vtb, const int* __restrict__ kpm,
    bf16* __restrict__ attnout) {
  __shared__ __align__(16) u16 Qs[128][64];
  __shared__ __align__(16) u16 Ks[64][64];
  __shared__ __align__(16) u16 Vt[64][64];  // [d][key]
  __shared__ __align__(16) u16 Ps[128][72];  // swizzled
  __shared__ float Ls[128];
  __shared__ int kbadS[64];
  int bid = blockIdx.x;
  int tile = bid & 31, bh = bid >> 5;
  int b = bh / HH, h = bh % HH;
  int tid = threadIdx.x, lane = tid & 63, w = tid >> 6;
  int quad = lane >> 4, t = lane & 15;
  const u16* qp = (const u16*)qb + (size_t)bh * SS * 64;
  const u16* kp = (const u16*)kb + (size_t)bh * SS * 64;
  const u16* vp = (const u16*)vtb + (size_t)bh * SS * 64;  // rows are d
  int sq0 = GG + tile * 128;
#pragma unroll
  for (int j = 0; j < 4; ++j) {
    int qr = sq0 + w * 32 + j * 8 + (lane >> 3);
    int sr = qr < SS ? qr : SS - 1;
    async_copy16(qp + (size_t)sr * 64 + (lane & 7) * 8, &Qs[w * 32 + j * 8][0]);
  }
  __syncthreads();
  short8v aq[2][2];
#pragma unroll
  for (int st = 0; st < 2; ++st)
#pragma unroll
    for (int ks = 0; ks < 2; ++ks)
      aq[st][ks] = *(const short8v*)&Qs[w * 32 + st * 16 + t][ks * 32 + quad * 8];
  floatx4 O[2][4];
#pragma unroll
  for (int st = 0; st < 2; ++st)
#pragma unroll
    for (int dt = 0; dt < 4; ++dt) O[st][dt] = (floatx4)(0.f);
  float ps[2][4] = {};
  int win_lo = max(sq0 - WW, GG);
  int win_hi = min(sq0 + 127 + WW, SS - 1);
  int kb_lo = win_lo & ~63;
  int iters = ((win_hi - kb_lo) >> 6) + 2;  // +1: global-keys block
  for (int it = 0; it < iters; ++it) {
    int kbs = (it == 0) ? 0 : kb_lo + ((it - 1) << 6);
    __syncthreads();
#pragma unroll
    for (int j = 0; j < 2; ++j) {
      async_copy16(kp + (size_t)(kbs + w * 16 + j * 8 + (lane >> 3)) * 64 +
                       (lane & 7) * 8,
                   &Ks[w * 16 + j * 8][0]);
      async_copy16(vp + (size_t)(w * 16 + j * 8 + (lane >> 3)) * SS + kbs +
                       (lane & 7) * 8,
                   &Vt[w * 16 + j * 8][0]);
    }
    if (tid < 64) kbadS[tid] = kpm[b * SS + kbs + tid];
    __syncthreads();
#pragma unroll
    for (int st = 0; st < 2; ++st) {
      floatx4 S[4];
#pragma unroll
      for (int nt = 0; nt < 4; ++nt) {
        S[nt] = (floatx4)(0.f);
#pragma unroll
        for (int ks = 0; ks < 2; ++ks) {
          short8v bk = *(const short8v*)&Ks[nt * 16 + t][ks * 32 + quad * 8];
          S[nt] = __builtin_amdgcn_mfma_f32_16x16x32_bf16(aq[st][ks], bk, S[nt],
                                                          0, 0, 0);
        }
      }
      int prow = w * 32 + st * 16 + quad * 4;
      if (it == 0) {
#pragma unroll
        for (int nt = 0; nt < 4; ++nt)
#pragma unroll
          for (int r = 0; r < 4; ++r) {
            float p = exp2f(S[nt][r]);
            ps[st][r] += p;
            Ps[prow + r][((nt ^ quad) << 4) + t] = f2bu(p);
          }
      } else {
#pragma unroll
        for (int r = 0; r < 4; ++r) {
          int qr = sq0 + prow + r;
          int off = kbs + t + WW - qr;
#pragma unroll
          for (int nt = 0; nt < 4; ++nt) {
            int bad = kbadS[nt * 16 + t];
            unsigned u = (unsigned)(off + nt * 16);
            float p = exp2f((u <= 2 * WW && bad == 0) ? S[nt][r] : -3.0e38f);
            ps[st][r] += p;
            Ps[prow + r][((nt ^ quad) << 4) + t] = f2bu(p);
          }
        }
      }
    }
    short8v ap[2][2];
#pragma unroll
    for (int st = 0; st < 2; ++st)
#pragma unroll
      for (int ks = 0; ks < 2; ++ks) {
        int chunk = (2 * ks + (quad >> 1)) ^ ((t >> 2) & 3);
        ap[st][ks] = *(const short8v*)&Ps[w * 32 + st * 16 + t]
                                        [(chunk << 4) + ((quad & 1) << 3)];
      }
#pragma unroll
    for (int dt = 0; dt < 4; ++dt) {
#pragma unroll
      for (int ks = 0; ks < 2; ++ks) {
        short8v av = *(const short8v*)&Vt[dt * 16 + t][ks * 32 + quad * 8];
#pragma unroll
        for (int st = 0; st < 2; ++st)
          O[st][dt] = __builtin_amdgcn_mfma_f32_16x16x32_bf16(av, ap[st][ks],
                                                              O[st][dt], 0, 0, 0);
      }
    }
  }
#pragma unroll
  for (int st = 0; st < 2; ++st) {
#pragma unroll
    for (int r = 0; r < 4; ++r)
#pragma unroll
      for (int off = 1; off < 16; off <<= 1) ps[st][r] += __shfl_xor(ps[st][r], off);
    if (t == 0)
#pragma unroll
      for (int r = 0; r < 4; ++r) Ls[w * 32 + st * 16 + quad * 4 + r] = ps[st][r];
  }
#pragma unroll
  for (int st = 0; st < 2; ++st) {
    int q = sq0 + w * 32 + st * 16 + t;
    if (q < SS) {
      float linv = 1.0f / Ls[w * 32 + st * 16 + t];
#pragma unroll
      for (int dt = 0; dt < 4; ++dt) {
        ushort4 o;
        o.x = f2bu(O[st][dt][0] * linv);
        o.y = f2bu(O[st][dt][1] * linv);
        o.z = f2bu(O[st][dt][2] * linv);
        o.w = f2bu(O[st][dt][3] * linv);
        *(ushort4*)((u16*)attnout + ((size_t)q * BB + b) * DD + h * 64 +
                    dt * 16 + quad * 4) = o;
      }
    }
  }
}

// Global-row attention (rows < G), 256-key segment per block; fp32 partials.
__global__ __launch_bounds__(256) void attn_glb(
    const bf16* __restrict__ qgb, const bf16* __restrict__ kgb,
    const bf16* __restrict__ vtb, const int* __restrict__ kpm,
    float* __restrict__ part) {
  __shared__ __align__(16) u16 Qs[64][72];
  __shared__ __align__(16) u16 Ks[64][72];
  __shared__ __align__(16) u16 Vt[64][72];
  __shared__ __align__(16) u16 Ps[64][72];
  __shared__ int kbadS[64];
  int bid = blockIdx.x;
  int bh = bid >> 4, seg = bid & 15;
  int b = bh / HH;
  int tid = threadIdx.x, lane = tid & 63, w = tid >> 6;
  int quad = lane >> 4, t = lane & 15;
  const u16* qp = (const u16*)qgb + (size_t)bh * GG * 64;
  const u16* kp = (const u16*)kgb + (size_t)bh * SS * 64;
  const u16* vp = (const u16*)vtb + (size_t)bh * SS * 64;  // rows are d
  int srow = tid >> 2, scol = (tid & 3) * 16;
#pragma unroll
  for (int i = 0; i < 4; ++i)
    *(ushort4*)&Qs[srow][scol + 4 * i] =
        *(const ushort4*)(qp + (size_t)srow * 64 + scol + 4 * i);
  __syncthreads();
  short8v aq[2];
#pragma unroll
  for (int ks = 0; ks < 2; ++ks)
    aq[ks] = *(const short8v*)&Qs[16 * w + t][ks * 32 + quad * 8];
  floatx4 O[4];
#pragma unroll
  for (int i = 0; i < 4; ++i) O[i] = (floatx4)(0.f);
  float ps[4] = {0.f, 0.f, 0.f, 0.f};
  for (int it = 0; it < 4; ++it) {
    int kbs = (seg << 8) + (it << 6);
    ushort4 ku[4], vu[4];
#pragma unroll
    for (int i = 0; i < 4; ++i) {
      ku[i] = *(const ushort4*)(kp + (size_t)(kbs + srow) * 64 + scol + 4 * i);
      vu[i] = *(const ushort4*)(vp + (size_t)srow * SS + kbs + scol + 4 * i);
    }
    int kbval = (tid < 64) ? kpm[b * SS + kbs + tid] : 0;
    __syncthreads();
#pragma unroll
    for (int i = 0; i < 4; ++i) {
      *(ushort4*)&Ks[srow][scol + 4 * i] = ku[i];
      *(ushort4*)&Vt[srow][scol + 4 * i] = vu[i];
    }
    if (tid < 64) kbadS[tid] = kbval;
    __syncthreads();
    floatx4 S[4];
#pragma unroll
    for (int nt = 0; nt < 4; ++nt) {
      S[nt] = (floatx4)(0.f);
#pragma unroll
      for (int ks = 0; ks < 2; ++ks) {
        short8v bk = *(const short8v*)&Ks[nt * 16 + t][ks * 32 + quad * 8];
        S[nt] = __builtin_amdgcn_mfma_f32_16x16x32_bf16(aq[ks], bk, S[nt], 0, 0, 0);
      }
    }
#pragma unroll
    for (int nt = 0; nt < 4; ++nt) {
      int bad = kbadS[nt * 16 + t];
#pragma unroll
      for (int r = 0; r < 4; ++r) {
        float p = exp2f((bad <= 0) ? S[nt][r] : -3.0e38f);
        ps[r] += p;
        Ps[16 * w + quad * 4 + r][((nt ^ quad) << 4) + t] = f2bu(p);
      }
    }
    short8v ap[2];
#pragma unroll
    for (int ks = 0; ks < 2; ++ks) {
      int chunk = (2 * ks + (quad >> 1)) ^ ((t >> 2) & 3);
      ap[ks] = *(const short8v*)&Ps[16 * w + t][(chunk << 4) + ((quad & 1) << 3)];
    }
#pragma unroll
    for (int dt = 0; dt < 4; ++dt)
#pragma unroll
      for (int ks = 0; ks < 2; ++ks) {
        short8v bv = *(const short8v*)&Vt[dt * 16 + t][ks * 32 + quad * 8];
        O[dt] = __builtin_amdgcn_mfma_f32_16x16x32_bf16(ap[ks], bv, O[dt], 0, 0, 0);
      }
  }
#pragma unroll
  for (int r = 0; r < 4; ++r)
#pragma unroll
    for (int off = 1; off < 16; off <<= 1) ps[r] += __shfl_xor(ps[r], off);
  float* pO = part + (size_t)bid * 4160;
#pragma unroll
  for (int dt = 0; dt < 4; ++dt)
#pragma unroll
    for (int r = 0; r < 4; ++r)
      pO[(16 * w + quad * 4 + r) * 64 + dt * 16 + t] = O[dt][r];
  if (t == 0)
#pragma unroll
    for (int r = 0; r < 4; ++r) pO[4096 + 16 * w + quad * 4 + r] = ps[r];
}

__global__ __launch_bounds__(256) void attn_comb(const float* __restrict__ part,
                                                 bf16* __restrict__ attnout) {
  int tid = threadIdx.x, lane = tid & 63, w = tid >> 6;
  int idx = blockIdx.x * 4 + w;  // [0, B*H*64)
  int bh = idx >> 6, row = idx & 63;
  int b = bh / HH, h = bh % HH;
  float o = 0.f, L = 0.f;
#pragma unroll
  for (int s16 = 0; s16 < 16; ++s16) {
    const float* p = part + (size_t)(bh * 16 + s16) * 4160;
    o += p[(row << 6) + lane];
    L += p[4096 + row];
  }
  attnout[((size_t)row * BB + b) * DD + h * 64 + lane] = __float2bfloat16(o / L);
}

extern "C" void kernel_launch(void* const* d_in, const int* in_sizes, int n_in,
                              void* d_out, int out_size, void* d_ws,
                              size_t ws_size, hipStream_t stream) {
  const int* kpm = (const int*)d_in[1];
  float* outp = (float*)d_out;
  const size_t SZ = (size_t)BB * HH * SS * 64;  // 6,291,456
  const size_t WSZ = (size_t)DD * DD;           // 589,824
  bf16* p = (bf16*)d_ws;
  bf16* cQ = p; p += SZ;        // canonical query
  bf16* cWt = p; p += 7 * WSZ;  // slots: q,k,v,kg,vg,qg,o
  bf16* cB = p; p += 7 * DD;
  bf16* q = p; p += SZ;   // heads [bh][s][d]   (gemm5c which=0..4 outputs
  bf16* k = p; p += SZ;   //  must stay contiguous in this order)
  bf16* v = p; p += SZ;   // TRANSPOSED [bh][d][s] (written by gemm5c)
  bf16* kg = p; p += SZ;  // heads
  bf16* vg = p; p += SZ;  // TRANSPOSED [bh][d][s] (written by gemm5c)
  bf16* qg = p; p += (size_t)BB * HH * GG * 64;
  bf16* attnout = p; p += SZ;
  float* part = (float*)p;  // 384 * 4160 floats
  int* flag = (int*)(part + (size_t)384 * 4160);
  dim3 blk(256);

  P7 wsrc{{d_in[2], d_in[4], d_in[6], d_in[10], d_in[12], d_in[8], d_in[14]}};
  P7 bsrc{{d_in[3], d_in[5], d_in[7], d_in[11], d_in[13], d_in[9], d_in[15]}};

  detect_dtype<<<1, blk, 0, stream>>>((const u16*)d_in[0], flag);
  prep<<<dim3(24, 24, 9), blk, 0, stream>>>(wsrc, bsrc, d_in[0], cWt, cB, cQ, flag);
  gemm5c<<<dim3(5 * 384 + 6), blk, 0, stream>>>(cQ, cWt, cB, q, qg);
  attn_local128<<<dim3(24 * 32), blk, 0, stream>>>(q, k, v, kpm, attnout);
  attn_glb<<<dim3(BB * HH * 16), blk, 0, stream>>>(qg, kg, vg, kpm, part);
  attn_comb<<<dim3(BB * HH * 16), blk, 0, stream>>>(part, attnout);
  gemm_out<<<dim3(384), blk, 0, stream>>>(attnout, cWt + 6 * WSZ, cB + 6 * DD, outp);
}